// Round 6
// baseline (258.358 us; speedup 1.0000x reference)
//
#include <hip/hip_runtime.h>

using short8   = __attribute__((ext_vector_type(8))) short;
using f32x4    = __attribute__((ext_vector_type(4))) float;
using ushort4v = __attribute__((ext_vector_type(4))) unsigned short;

#define BN_EPS 1e-5f
// log2(e)/sqrt(32): folded into q projection so softmax uses native exp2
#define ATT_SCALE_LOG2E 0.2550348347988049f

__device__ __forceinline__ unsigned short f2bf(float f) {
    union { float f; unsigned u; } v; v.f = f;
    return (unsigned short)((v.u + 0x7FFFu + ((v.u >> 16) & 1u)) >> 16);  // RNE
}

// pack two f32 -> two bf16 RNE-ish (round-half-up): for proj epilogue
__device__ __forceinline__ unsigned pack2bf(float a, float b) {
    union { float f; unsigned u; } ua, ub; ua.f = a; ub.f = b;
    return __builtin_amdgcn_perm(ub.u + 0x8000u, ua.u + 0x8000u, 0x07060302u);
}

// pack two f32 -> two bf16 TRUNCATED (1 v_perm): P entries only. The ~0.2%
// downward bias hits numerator and denominator alike -> cancels to 1st order.
__device__ __forceinline__ unsigned pack2bf_t(float a, float b) {
    union { float f; unsigned u; } ua, ub; ua.f = a; ub.f = b;
    return __builtin_amdgcn_perm(ub.u, ua.u, 0x07060302u);
}

// async global->LDS, 16B per lane. lp: wave-uniform base (HW adds lane*16).
__device__ __forceinline__ void glds16(const void* gp, void* lp) {
    __builtin_amdgcn_global_load_lds(
        (const __attribute__((address_space(1))) unsigned*)gp,
        (__attribute__((address_space(3))) unsigned*)lp, 16, 0, 0);
}

// ---------------------------------------------------------------------------
// Kernel 0: weights -> bf16; fold conv-bias + BN into per-row (scale, offset).
// Rows: 0-31 q, 32-63 k, 64-319 v.
// ---------------------------------------------------------------------------
__global__ void prep_kernel(
    const float* __restrict__ qw, const float* __restrict__ qb,
    const float* __restrict__ qg, const float* __restrict__ qbe,
    const float* __restrict__ qm, const float* __restrict__ qv,
    const float* __restrict__ kw, const float* __restrict__ kb,
    const float* __restrict__ kg, const float* __restrict__ kbe,
    const float* __restrict__ km, const float* __restrict__ kvv,
    const float* __restrict__ vw, const float* __restrict__ vb,
    const float* __restrict__ vg, const float* __restrict__ vbe,
    const float* __restrict__ vm, const float* __restrict__ vv,
    unsigned short* __restrict__ wq, float* __restrict__ scale,
    float* __restrict__ off)
{
    int r = blockIdx.x;      // 0..319
    int t = threadIdx.x;     // 0..63
    const float *wsrc, *g, *be, *mn, *vr, *bi;
    int rl;
    if (r < 32)      { rl = r;      wsrc = qw; g = qg; be = qbe; mn = qm; vr = qv;  bi = qb; }
    else if (r < 64) { rl = r - 32; wsrc = kw; g = kg; be = kbe; mn = km; vr = kvv; bi = kb; }
    else             { rl = r - 64; wsrc = vw; g = vg; be = vbe; mn = vm; vr = vv;  bi = vb; }

    float4 w4 = *(const float4*)(wsrc + rl * 256 + t * 4);
    ushort4v o;
    o.x = f2bf(w4.x); o.y = f2bf(w4.y); o.z = f2bf(w4.z); o.w = f2bf(w4.w);
    *(ushort4v*)(wq + r * 256 + t * 4) = o;

    if (t == 0) {
        float inv = g[rl] * rsqrtf(vr[rl] + BN_EPS);
        float ofv = bi[rl] * inv + be[rl] - mn[rl] * inv;
        float s = (r < 32) ? ATT_SCALE_LOG2E : 1.0f;
        scale[r] = inv * s;
        off[r]   = ofv * s;
    }
}

// ---------------------------------------------------------------------------
// Kernel 1: projections. bx = ((b*64+nt)<<1) | g ;
//   g=0: q (stages x1)
//   g=1: k AND all 256 v rows (stages x2 ONCE -> x2 HBM read 1x, was 3x)
// q_t/k_t: [b][n][32] bf16.  v_ws: tile-blocked [b*64+nt][256][64] bf16.
// ---------------------------------------------------------------------------
#define XT_PITCH 264

__global__ __launch_bounds__(256, 2) void proj_kernel(
    const float* __restrict__ x1, const float* __restrict__ x2,
    const unsigned short* __restrict__ wq,
    const float* __restrict__ scale, const float* __restrict__ off,
    unsigned short* __restrict__ q_t, unsigned short* __restrict__ k_t,
    unsigned short* __restrict__ v_ws)
{
    __shared__ __align__(16) unsigned short Xt[64 * XT_PITCH];   // 33792 B
    int bx = blockIdx.x;
    int g  = bx & 1;
    int t2 = bx >> 1;
    int nt = t2 & 63;
    int b  = t2 >> 6;
    int n0 = nt * 64;
    int tid = threadIdx.x;
    int wv = tid >> 6, lane = tid & 63;
    int m16 = lane & 15, qd = lane >> 4;

    const float* xb = ((g == 0) ? x1 : x2) + (size_t)b * 256 * 4096 + n0 + lane;

    // octet-gather transpose: n = lane, channels 8*o..8*o+7, o = wv*8+i
    #pragma unroll 2
    for (int i = 0; i < 8; ++i) {
        int o = wv * 8 + i;                       // 0..31
        const float* src = xb + (size_t)(o * 8) * 4096;
        uint4 dw;
        dw.x = pack2bf(src[0],                src[(size_t)1 * 4096]);
        dw.y = pack2bf(src[(size_t)2 * 4096], src[(size_t)3 * 4096]);
        dw.z = pack2bf(src[(size_t)4 * 4096], src[(size_t)5 * 4096]);
        dw.w = pack2bf(src[(size_t)6 * 4096], src[(size_t)7 * 4096]);
        *(uint4*)&Xt[lane * XT_PITCH + o * 8] = dw;
    }
    __syncthreads();

    f32x4 zero4 = {0.f, 0.f, 0.f, 0.f};

    // ---- q (g=0) or k (g=1) projection: 32 rows ----
    {
        int rb = g * 32;
        f32x4 acc0 = zero4, acc1 = zero4;
        #pragma unroll 2
        for (int s = 0; s < 8; ++s) {
            short8 w0 = *(const short8*)(wq + (size_t)(rb +      m16) * 256 + s * 32 + qd * 8);
            short8 w1 = *(const short8*)(wq + (size_t)(rb + 16 + m16) * 256 + s * 32 + qd * 8);
            short8 xf = *(const short8*)&Xt[(16 * wv + m16) * XT_PITCH + s * 32 + qd * 8];
            acc0 = __builtin_amdgcn_mfma_f32_16x16x32_bf16(w0, xf, acc0, 0, 0, 0);
            acc1 = __builtin_amdgcn_mfma_f32_16x16x32_bf16(w1, xf, acc1, 0, 0, 0);
        }
        unsigned short* dst = (g == 0) ? q_t : k_t;
        int ncol = n0 + 16 * wv + m16;
        #pragma unroll
        for (int tm = 0; tm < 2; ++tm) {
            f32x4 acc = tm ? acc1 : acc0;
            int r0 = 16 * tm + 4 * qd;
            float4 sc = *(const float4*)(scale + rb + r0);
            float4 of = *(const float4*)(off   + rb + r0);
            ushort4v o;
            o.x = f2bf(acc.x * sc.x + of.x);
            o.y = f2bf(acc.y * sc.y + of.y);
            o.z = f2bf(acc.z * sc.z + of.z);
            o.w = f2bf(acc.w * sc.w + of.w);
            *(ushort4v*)(dst + ((size_t)b * 4096 + ncol) * 32 + r0) = o;
        }
    }

    // ---- v projection (g=1 only): all 256 rows ----
    if (g == 1) {
        f32x4 acc[4][4];
        #pragma unroll
        for (int rr = 0; rr < 4; ++rr)
            #pragma unroll
            for (int tm = 0; tm < 4; ++tm) acc[rr][tm] = zero4;
        #pragma unroll 2
        for (int s = 0; s < 8; ++s) {
            short8 xf[4];
            #pragma unroll
            for (int tm = 0; tm < 4; ++tm)
                xf[tm] = *(const short8*)&Xt[(16 * tm + m16) * XT_PITCH + s * 32 + qd * 8];
            #pragma unroll
            for (int rr = 0; rr < 4; ++rr) {
                short8 wf = *(const short8*)(wq + (size_t)(64 + rr * 64 + 16 * wv + m16) * 256 + s * 32 + qd * 8);
                #pragma unroll
                for (int tm = 0; tm < 4; ++tm)
                    acc[rr][tm] = __builtin_amdgcn_mfma_f32_16x16x32_bf16(xf[tm], wf, acc[rr][tm], 0, 0, 0);
            }
        }
        unsigned short* vt = v_ws + (size_t)(b * 64 + nt) * 256 * 64;
        #pragma unroll
        for (int rr = 0; rr < 4; ++rr) {
            int c = rr * 64 + 16 * wv + m16;
            float sc = scale[64 + c], of = off[64 + c];
            #pragma unroll
            for (int tm = 0; tm < 4; ++tm) {
                int nloc = 16 * tm + 4 * qd;
                ushort4v o;
                o.x = f2bf(acc[rr][tm].x * sc + of);
                o.y = f2bf(acc[rr][tm].y * sc + of);
                o.z = f2bf(acc[rr][tm].z * sc + of);
                o.w = f2bf(acc[rr][tm].w * sc + of);
                *(ushort4v*)(vt + c * 64 + nloc) = o;
            }
        }
    }
}

// ---------------------------------------------------------------------------
// Kernel 2: flash attention, LDS-port-relieved.
// 1024 blocks x 2 waves (4 blocks/CU, 8 waves/CU). Wave = 32q x 64ch x all
// keys. K: async-DMA staged (dbuf, swizzled). V: DIRECT GLOBAL per-lane b128
// loads (L2-resident, ~1MB/XCD working set), issued right after the barrier
// so the S->exp->P-RT chain (~400cyc) hides L2 latency — V off the LDS pipe
// cuts block LDS traffic ~46%. P: wave-private swizzled LDS round-trip.
// Row sums via ones-MFMA (Do rows == acc rows -> shuffle-free epilogue).
// ---------------------------------------------------------------------------
__global__ __launch_bounds__(128, 2) void flash_kernel(
    const unsigned short* __restrict__ q_t, const unsigned short* __restrict__ k_t,
    const unsigned short* __restrict__ v_ws, float* __restrict__ out)
{
    __shared__ __align__(16) unsigned char Smem[16384]; // K dbuf 2x4KB + P 2x4KB

    int bx  = blockIdx.x;
    int cg  = bx & 3;
    int b   = (bx >> 2) & 3;
    int qg  = bx >> 4;             // 0..63
    int tid = threadIdx.x;
    int wv  = tid >> 6, lane = tid & 63;
    int m16 = lane & 15, qd = lane >> 4;

    int q0 = qg * 64 + wv * 32;
    int c0 = cg * 64;
    int sw = m16 & 7;

    // K staging addresses (16B-granule swizzle folded into global source)
    int kg[2], kl[2];
    #pragma unroll
    for (int u = 0; u < 2; ++u) {
        int slot = (wv * 2 + u) * 64 + lane;
        int row = slot >> 2, pos = slot & 3;
        kg[u] = (row * 4 + (pos ^ (row & 3))) * 16;
        kl[u] = (wv * 2 + u) * 1024;
    }

    const char* kbase = (const char*)k_t + (size_t)b * 262144;
    const unsigned short* vbase = v_ws + (size_t)b * 1048576
                                + (size_t)(c0 + m16) * 64 + qd * 8;
    char* smem = (char*)Smem;

    const unsigned short* qb = q_t + (size_t)b * 131072;
    short8 Qf0 = *(const short8*)(qb + (size_t)(q0 +      m16) * 32 + qd * 8);
    short8 Qf1 = *(const short8*)(qb + (size_t)(q0 + 16 + m16) * 32 + qd * 8);

    const short bf1 = (short)0x3F80;
    short8 ones = {bf1, bf1, bf1, bf1, bf1, bf1, bf1, bf1};

    f32x4 zero4 = {0.f, 0.f, 0.f, 0.f};
    f32x4 acc[2][4];
    f32x4 Do[2] = {zero4, zero4};
    #pragma unroll
    for (int mt = 0; mt < 2; ++mt)
        #pragma unroll
        for (int cs = 0; cs < 4; ++cs) acc[mt][cs] = zero4;

    unsigned short* Pw = (unsigned short*)(smem + 8192 + wv * 4096);
    int wr0 = m16 * 64 + (qd & 1) * 4;
    int wr1 = wr0 + 1024;
    int ch  = qd >> 1;
    int kro = m16 * 64 + ((qd ^ (m16 & 3)) << 4);

    // prologue: stage K tile 0 into buf 0
    glds16(kbase + kg[0], smem + kl[0]);
    glds16(kbase + kg[1], smem + kl[1]);

    #pragma unroll 1
    for (int it = 0; it < 64; ++it) {
        int z = it & 1;
        __syncthreads();   // K buf z ready (DMA issued one full tile ago)

        if (it < 63) {     // stage next K tile into buf z^1
            const char* ks = kbase + (size_t)(it + 1) * 4096;
            char* kd = smem + (z ^ 1) * 4096;
            glds16(ks + kg[0], kd + kl[0]);
            glds16(ks + kg[1], kd + kl[1]);
        }

        // V for THIS tile: direct global b128 loads (L2), ~400cyc before use
        const unsigned short* vt = vbase + (size_t)it * 16384;
        short8 Vf[4][2];
        #pragma unroll
        for (int cs = 0; cs < 4; ++cs) {
            Vf[cs][0] = *(const short8*)(vt + cs * 1024);
            Vf[cs][1] = *(const short8*)(vt + cs * 1024 + 32);
        }

        const char* Kb = smem + z * 4096;

        #pragma unroll
        for (int t = 0; t < 2; ++t) {
            // ---- K fragments from staged LDS (swizzled, 2-way = free) ----
            short8 Kf0 = *(const short8*)(Kb + t * 2048 + kro);
            short8 Kf1 = *(const short8*)(Kb + t * 2048 + 1024 + kro);

            // ---- S^T = K.Q^T ----
            f32x4 S00 = __builtin_amdgcn_mfma_f32_16x16x32_bf16(Kf0, Qf0, zero4, 0, 0, 0);
            f32x4 S01 = __builtin_amdgcn_mfma_f32_16x16x32_bf16(Kf1, Qf0, zero4, 0, 0, 0);
            f32x4 S10 = __builtin_amdgcn_mfma_f32_16x16x32_bf16(Kf0, Qf1, zero4, 0, 0, 0);
            f32x4 S11 = __builtin_amdgcn_mfma_f32_16x16x32_bf16(Kf1, Qf1, zero4, 0, 0, 0);

            // ---- exp2 + trunc-pack + swizzled wave-private P write ----
            int k0 = ((4 * t +     ch) ^ sw) * 8;
            int k1 = ((4 * t + 2 + ch) ^ sw) * 8;
            uint2 w;
            w.x = pack2bf_t(__builtin_amdgcn_exp2f(S00.x), __builtin_amdgcn_exp2f(S00.y));
            w.y = pack2bf_t(__builtin_amdgcn_exp2f(S00.z), __builtin_amdgcn_exp2f(S00.w));
            *(uint2*)&Pw[wr0 + k0] = w;
            w.x = pack2bf_t(__builtin_amdgcn_exp2f(S01.x), __builtin_amdgcn_exp2f(S01.y));
            w.y = pack2bf_t(__builtin_amdgcn_exp2f(S01.z), __builtin_amdgcn_exp2f(S01.w));
            *(uint2*)&Pw[wr0 + k1] = w;
            w.x = pack2bf_t(__builtin_amdgcn_exp2f(S10.x), __builtin_amdgcn_exp2f(S10.y));
            w.y = pack2bf_t(__builtin_amdgcn_exp2f(S10.z), __builtin_amdgcn_exp2f(S10.w));
            *(uint2*)&Pw[wr1 + k0] = w;
            w.x = pack2bf_t(__builtin_amdgcn_exp2f(S11.x), __builtin_amdgcn_exp2f(S11.y));
            w.y = pack2bf_t(__builtin_amdgcn_exp2f(S11.z), __builtin_amdgcn_exp2f(S11.w));
            *(uint2*)&Pw[wr1 + k1] = w;

            // ---- A-fragments back (same-wave lgkm dependency only) ----
            int rk = ((4 * t + qd) ^ sw) * 8;
            short8 Ap0 = *(const short8*)&Pw[m16 * 64 + rk];
            short8 Ap1 = *(const short8*)&Pw[1024 + m16 * 64 + rk];

            // ---- PV + ones row-sum (Do rows == acc rows) ----
            Do[0] = __builtin_amdgcn_mfma_f32_16x16x32_bf16(Ap0, ones, Do[0], 0, 0, 0);
            Do[1] = __builtin_amdgcn_mfma_f32_16x16x32_bf16(Ap1, ones, Do[1], 0, 0, 0);
            acc[0][0] = __builtin_amdgcn_mfma_f32_16x16x32_bf16(Ap0, Vf[0][t], acc[0][0], 0, 0, 0);
            acc[0][1] = __builtin_amdgcn_mfma_f32_16x16x32_bf16(Ap0, Vf[1][t], acc[0][1], 0, 0, 0);
            acc[0][2] = __builtin_amdgcn_mfma_f32_16x16x32_bf16(Ap0, Vf[2][t], acc[0][2], 0, 0, 0);
            acc[0][3] = __builtin_amdgcn_mfma_f32_16x16x32_bf16(Ap0, Vf[3][t], acc[0][3], 0, 0, 0);
            acc[1][0] = __builtin_amdgcn_mfma_f32_16x16x32_bf16(Ap1, Vf[0][t], acc[1][0], 0, 0, 0);
            acc[1][1] = __builtin_amdgcn_mfma_f32_16x16x32_bf16(Ap1, Vf[1][t], acc[1][1], 0, 0, 0);
            acc[1][2] = __builtin_amdgcn_mfma_f32_16x16x32_bf16(Ap1, Vf[2][t], acc[1][2], 0, 0, 0);
            acc[1][3] = __builtin_amdgcn_mfma_f32_16x16x32_bf16(Ap1, Vf[3][t], acc[1][3], 0, 0, 0);
        }
    }

    // ---- epilogue: divide by ones-MFMA row sums (row-aligned, no shuffles) --
    f32x4 inv[2];
    #pragma unroll
    for (int mt = 0; mt < 2; ++mt) {
        inv[mt].x = __builtin_amdgcn_rcpf(Do[mt].x);
        inv[mt].y = __builtin_amdgcn_rcpf(Do[mt].y);
        inv[mt].z = __builtin_amdgcn_rcpf(Do[mt].z);
        inv[mt].w = __builtin_amdgcn_rcpf(Do[mt].w);
    }

    float* ob = out + ((size_t)b * 256 + c0) * 4096 + q0;
    #pragma unroll
    for (int mt = 0; mt < 2; ++mt)
        #pragma unroll
        for (int cs = 0; cs < 4; ++cs) {
            float4 o;
            o.x = acc[mt][cs].x * inv[mt].x;
            o.y = acc[mt][cs].y * inv[mt].y;
            o.z = acc[mt][cs].z * inv[mt].z;
            o.w = acc[mt][cs].w * inv[mt].w;
            *(float4*)(ob + (size_t)(cs * 16 + m16) * 4096 + mt * 16 + qd * 4) = o;
        }
}

// ---------------------------------------------------------------------------
// Workspace: wq 320x256 bf16 | scale/off 320 f32 | q_t,k_t [b][n][32] bf16 |
// v_ws tile-blocked [b*64+kt][256][64] bf16. Total ~10.7 MB.
// ---------------------------------------------------------------------------
extern "C" void kernel_launch(void* const* d_in, const int* in_sizes, int n_in,
                              void* d_out, int out_size, void* d_ws, size_t ws_size,
                              hipStream_t stream)
{
    const float* x1  = (const float*)d_in[0];
    const float* x2  = (const float*)d_in[1];
    const float* qw  = (const float*)d_in[2];
    const float* qb  = (const float*)d_in[3];
    const float* qg  = (const float*)d_in[4];
    const float* qbe = (const float*)d_in[5];
    const float* qm  = (const float*)d_in[6];
    const float* qv  = (const float*)d_in[7];
    const float* kw  = (const float*)d_in[8];
    const float* kb  = (const float*)d_in[9];
    const float* kg  = (const float*)d_in[10];
    const float* kbe = (const float*)d_in[11];
    const float* km  = (const float*)d_in[12];
    const float* kvv = (const float*)d_in[13];
    const float* vw  = (const float*)d_in[14];
    const float* vb  = (const float*)d_in[15];
    const float* vg  = (const float*)d_in[16];
    const float* vbe = (const float*)d_in[17];
    const float* vm  = (const float*)d_in[18];
    const float* vv  = (const float*)d_in[19];

    char* ws = (char*)d_ws;
    unsigned short* wq   = (unsigned short*)(ws + 0);
    float*          scale= (float*)(ws + 163840);
    float*          off  = (float*)(ws + 165120);
    unsigned short* q_t  = (unsigned short*)(ws + 166400);
    unsigned short* k_t  = (unsigned short*)(ws + 166400 + 1048576);
    unsigned short* v_ws = (unsigned short*)(ws + 166400 + 2097152);

    prep_kernel<<<320, 64, 0, stream>>>(qw, qb, qg, qbe, qm, qv,
                                        kw, kb, kg, kbe, km, kvv,
                                        vw, vb, vg, vbe, vm, vv,
                                        wq, scale, off);
    proj_kernel<<<512, 256, 0, stream>>>(x1, x2, wq, scale, off, q_t, k_t, v_ws);
    flash_kernel<<<1024, 128, 0, stream>>>(q_t, k_t, v_ws, (float*)d_out);
}